// Round 14
// baseline (425.498 us; speedup 1.0000x reference)
//
#include <hip/hip_runtime.h>
#include <math.h>

// LinearAttention: T=1024, D=256, H=256.  R14: ONE plain dispatch, 512 blocks,
// producer/consumer via device-scope flags (no cooperative launch: R11 showed
// coop costs ~70us; R13 showed redundant projections cost ~60us).
// Even blocks = R12-proven 512-thr MFMA projections (job=bid/2).
// Odd blocks  = R10-proven attn+MLP+LN (rows=(bid/2)*4..), which first do the
// K1-independent mask derivation, then spin on 256 per-worker MAGIC flags.
// Safety: all 512 blocks co-resident (2/CU: 16<=32 waves, LDS sum ~43KB<=160KB,
// VGPR fine) -> workers always run -> no hang mode. Flags need NO init: poison
// (0xAA..) != MAGIC clears stale values between replays; workers store MAGIC
// unconditionally after __threadfence.

typedef unsigned long long u64;
typedef unsigned short u16;
typedef unsigned int u32;
typedef __attribute__((ext_vector_type(8))) unsigned short us8;
typedef __attribute__((ext_vector_type(4))) unsigned short us4;
typedef __attribute__((ext_vector_type(8))) short s8;
typedef __attribute__((ext_vector_type(4))) float f4;

#define MAGIC 0x13579BDFu

__device__ __forceinline__ float eluf(float v) { return v > 0.f ? v : expm1f(v); }
__device__ __forceinline__ float mishf(float v) {
  float sp = fmaxf(v, 0.f) + log1pf(expf(-fabsf(v)));
  return v * tanhf(sp);
}
__device__ __forceinline__ u16 f2bf(float f) {
  unsigned u = __float_as_uint(f);
  unsigned r = u + 0x7FFFu + ((u >> 16) & 1u);
  return (u16)(r >> 16);
}
__device__ __forceinline__ float bf2f(u16 h) { return __uint_as_float((unsigned)h << 16); }

__device__ __forceinline__ f4 mfma16(const u16* a, const u16* b, f4 c) {
  s8 av = *(const s8*)(const void*)a;
  s8 bv = *(const s8*)(const void*)b;
  return __builtin_amdgcn_mfma_f32_16x16x32_bf16(av, bv, c, 0, 0, 0);
}

__device__ __forceinline__ u64 expand32(u64 x) {
  x &= 0xFFFFFFFFull;
  x = (x | (x << 16)) & 0x0000FFFF0000FFFFull;
  x = (x | (x << 8))  & 0x00FF00FF00FF00FFull;
  x = (x | (x << 4))  & 0x0F0F0F0F0F0F0F0Full;
  x = (x | (x << 2))  & 0x3333333333333333ull;
  x = (x | (x << 1))  & 0x5555555555555555ull;
  return x | (x << 1);
}

__device__ __forceinline__ us8 cvt8v(float4 a, float4 b) {
  us8 v;
  v[0] = f2bf(a.x); v[1] = f2bf(a.y); v[2] = f2bf(a.z); v[3] = f2bf(a.w);
  v[4] = f2bf(b.x); v[5] = f2bf(b.y); v[6] = f2bf(b.z); v[7] = f2bf(b.w);
  return v;
}

struct WSm {  // worker (R12 K1): double-buffered staging
  u16 Xs[2][2560];
  u16 Ws[2][2560];
  float scrK[128];
};
struct CSm {  // consumer (R10 K2)
  u64 GS[37];
  u64 Mw[64];
  u16 As[16 * 264];
  float Op[8][256];
  float dp[8];
  float Hbuf[4 * 260];
};

__global__ __launch_bounds__(512) void fused2(
    const float* __restrict__ x, const float* __restrict__ Wk,
    const float* __restrict__ Wq, const float* __restrict__ Wv,
    const float* __restrict__ Wsk, const float* __restrict__ bskip,
    const int* __restrict__ start, const int* __restrict__ done,
    const float* __restrict__ W1, const float* __restrict__ W2,
    const float* __restrict__ W3, const float* __restrict__ b1,
    const float* __restrict__ b2, const float* __restrict__ b3,
    const float* __restrict__ lnw, const float* __restrict__ lnb,
    u16* __restrict__ Kb, u16* __restrict__ Qb, u16* __restrict__ Vb,
    float* __restrict__ SKP, float* __restrict__ Kpart, u16* __restrict__ Wb,
    u32* __restrict__ Flg, float* __restrict__ outp) {
  __shared__ union { WSm w; CSm c; } S;
  const int tid = threadIdx.x, wave = tid >> 6, l = tid & 63;
  const int l15 = l & 15, quad = l >> 4;

  if ((blockIdx.x & 1) == 0) {
    // ================= WORKER (R12-proven K1 body) =================
    const int job = blockIdx.x >> 1;
    const int rt = job & 15, my = job >> 4;
    const int mat = my >> 2, nt = my & 3;
    const int n0 = nt * 64, mbase = rt * 64;
    const float* Wsrc = (mat == 0) ? Wk : (mat == 1) ? Wq : (mat == 2) ? Wv : Wsk;
    if (tid < 192) {  // side-job: bf16-convert MLP weights
      int cidx = job * 768 + tid * 4;
      const float* Wm = (cidx < 65536) ? W1 : (cidx < 131072) ? W2 : W3;
      float4 v = *(const float4*)(Wm + (cidx & 65535));
      us4 o; o.x = f2bf(v.x); o.y = f2bf(v.y); o.z = f2bf(v.z); o.w = f2bf(v.w);
      *(us4*)&Wb[cidx] = o;
    }
    const int sidx = tid & 255, srow = sidx >> 2, sko = (sidx & 3) * 8;
    const int isB = tid >> 8;
    const float* src = (isB ? Wsrc + (size_t)(n0 + srow) * 256
                            : x + (size_t)(mbase + srow) * 256) + sko;
    u16* dstb = (isB ? &S.w.Ws[0][0] : &S.w.Xs[0][0]) + srow * 40 + sko;
    const int st = wave & 3, sh = (wave >> 2) * 2;
    f4 acc0 = (f4){0.f, 0.f, 0.f, 0.f}, acc1 = (f4){0.f, 0.f, 0.f, 0.f};
    float4 pa = *(const float4*)src, pb = *(const float4*)(src + 4);
#pragma unroll 1
    for (int kt = 0; kt < 8; kt++) {
      const int p = kt & 1;
      *(us8*)(dstb + p * 2560) = cvt8v(pa, pb);
      if (kt < 7) {
        pa = *(const float4*)(src + (kt + 1) * 32);
        pb = *(const float4*)(src + (kt + 1) * 32 + 4);
      }
      __syncthreads();
      const u16* ap = &S.w.Xs[p][(st * 16 + l15) * 40 + quad * 8];
      acc0 = mfma16(ap, &S.w.Ws[p][(sh * 16 + l15) * 40 + quad * 8], acc0);
      acc1 = mfma16(ap, &S.w.Ws[p][((sh + 1) * 16 + l15) * 40 + quad * 8], acc1);
    }
    const int mw = mbase + st * 16 + quad * 4;
    if (mat == 0) {
      float tw[4];
#pragma unroll
      for (int r = 0; r < 4; r++) {
        float v0 = eluf(acc0[r]), v1 = eluf(acc1[r]);
        Kb[(mw + r) * 256 + n0 + sh * 16 + l15] = f2bf(v0);
        Kb[(mw + r) * 256 + n0 + (sh + 1) * 16 + l15] = f2bf(v1);
        tw[r] = v0 + v1;
      }
#pragma unroll
      for (int r = 0; r < 4; r++) {
        float t = tw[r];
#pragma unroll
        for (int off = 1; off <= 8; off <<= 1) t += __shfl_xor(t, off);
        if (l15 == 0) S.w.scrK[st * 32 + (wave >> 2) * 16 + quad * 4 + r] = t;
      }
      __syncthreads();
      if (wave < 4 && l < 16)
        Kpart[nt * 1024 + mbase + wave * 16 + l] =
            S.w.scrK[wave * 32 + l] + S.w.scrK[wave * 32 + 16 + l];
    } else if (mat == 1) {
#pragma unroll
      for (int r = 0; r < 4; r++) {
        Qb[(mw + r) * 256 + n0 + sh * 16 + l15] = f2bf(eluf(acc0[r]));
        Qb[(mw + r) * 256 + n0 + (sh + 1) * 16 + l15] = f2bf(eluf(acc1[r]));
      }
    } else if (mat == 2) {
#pragma unroll
      for (int r = 0; r < 4; r++) {
        Vb[(mw + r) * 256 + n0 + sh * 16 + l15] = f2bf(acc0[r]);
        Vb[(mw + r) * 256 + n0 + (sh + 1) * 16 + l15] = f2bf(acc1[r]);
      }
    } else {
      float bv0 = bskip[n0 + sh * 16 + l15], bv1 = bskip[n0 + (sh + 1) * 16 + l15];
#pragma unroll
      for (int r = 0; r < 4; r++) {
        SKP[(mw + r) * 256 + n0 + sh * 16 + l15] = acc0[r] + bv0;
        SKP[(mw + r) * 256 + n0 + (sh + 1) * 16 + l15] = acc1[r] + bv1;
      }
    }
    __threadfence();   // make this thread's global writes device-visible
    __syncthreads();   // all threads' writes done before flag
    if (tid == 0)
      __hip_atomic_store(&Flg[job], MAGIC, __ATOMIC_RELEASE, __HIP_MEMORY_SCOPE_AGENT);
    return;
  }

  // ================= CONSUMER (R10-proven K2 body) =================
  const int cb = blockIdx.x >> 1;
  const int m0 = cb * 4;
  // gates via ballot, direct global reads
  for (int job = wave; job < 37; job += 8) {
    int lv, w;
    if (job < 17)      { lv = 0; w = job; }
    else if (job < 25) { lv = 1; w = job - 17; }
    else if (job < 29) { lv = 2; w = job - 25; }
    else if (job < 31) { lv = 3; w = job - 29; }
    else               { lv = job - 27; w = 0; }
    int n = 1024 >> lv;
    int j = w * 64 + l;
    int ok = 0;
    if (j < n)
      ok = (j & 1) ? (done[((j + 1) << lv) - 1] != 0) : (start[((j + 2) << lv) - 1] != 0);
    u64 word = __ballot(ok != 0);
    if (l == 0) S.c.GS[(lv == 0) ? w : (lv == 1) ? 17 + w : (lv == 2) ? 25 + w
                       : (lv == 3) ? 29 + w : 27 + lv] = word;
  }
  __syncthreads();
  // wave-local ancestor chains. waves 0..3 = rows m0+wave+1.
  const int GOFF2[10] = {0, 17, 25, 29, 31, 32, 33, 34, 35, 36};
  if (wave < 4) {
    const int t = m0 + wave + 1;
    int rr10 = t;
#pragma unroll
    for (int qq = 0; qq < 10; qq++) rr10 = (rr10 & 1) ? (rr10 >> 1) : (rr10 >> 1) - 1;
    u64 cur = (l == 0 && rr10 == 0) ? 1ull : 0ull;
#pragma unroll 1
    for (int lv = 9; lv >= 1; lv--) {
      int rr = t;
      for (int qq = 0; qq < lv; qq++) rr = (rr & 1) ? (rr >> 1) : (rr >> 1) - 1;
      const int nw = (lv >= 4) ? 1 : (8 >> (lv - 1));
      u64 pw = __shfl(cur, l >> 1);
      u64 word;
      if (rr <= 0) word = (l == 0 && rr == 0) ? 1ull : 0ull;
      else {
        u64 e = 0;
        if (l < nw) e = expand32((l & 1) ? (pw >> 32) : pw) & S.c.GS[GOFF2[lv] + l];
        if (rr & 1) word = e;
        else {
          int gi = ((rr + 1) << lv) - 1;
          word = (start[gi] != 0) ? e : 0ull;
          if ((rr >> 6) == l) word |= (u64)(done[gi] != 0) << (rr & 63);
        }
        if (l >= nw) word = 0ull;
      }
      cur = word;
    }
    u64 pw = __shfl(cur, (l >> 1) & 7);
    u64 uw = 0;
    if (l <= 16) {
      u64 e = 0;
      if (l < 16) e = expand32((l & 1) ? (pw >> 32) : pw) & S.c.GS[l];
      if (t & 1) uw = e;
      else {
        uw = (start[t] != 0) ? e : 0ull;
        if ((t >> 6) == l) uw |= (u64)(done[t] != 0) << (t & 63);
      }
    }
    u64 nxt = __shfl(uw, (l + 1) & 63);
    u64 mw0 = (uw >> 1) | (nxt << 63);
    if (l < 16) S.c.Mw[wave * 16 + l] = mw0;
  }
  __syncthreads();
  // spin until all 256 workers have released their flag
  for (;;) {
    int ok4 = 1;
#pragma unroll
    for (int i = 0; i < 4; i++) {
      u32 v = __hip_atomic_load(&Flg[l * 4 + i], __ATOMIC_ACQUIRE, __HIP_MEMORY_SCOPE_AGENT);
      ok4 &= (v == MAGIC);
    }
    if (__ballot(ok4 != 0) == ~0ull) break;
    __builtin_amdgcn_s_sleep(32);
  }
  // phase B: sparse gather, 2-bit ILP; d from Kpart at set bits only.
  const int r = wave & 3, h = wave >> 2;
  const int tp = m0 + r;
  float q[4], O[4] = {0.f, 0.f, 0.f, 0.f};
  {
    us4 qv = *(const us4*)&Qb[tp * 256 + l * 4];
    q[0] = bf2f(qv.x); q[1] = bf2f(qv.y); q[2] = bf2f(qv.z); q[3] = bf2f(qv.w);
  }
  float qs = q[0] + q[1] + q[2] + q[3];
#pragma unroll
  for (int off = 1; off <= 32; off <<= 1) qs += __shfl_xor(qs, off);
  float d = 0.f;
  for (int w = h * 8; w < h * 8 + 8; w++) {
    u64 bits = S.c.Mw[r * 16 + w];
    while (bits) {
      int b0 = __builtin_ctzll(bits); bits &= bits - 1;
      int j0 = w * 64 + b0;
      if (bits) {
        int b1x = __builtin_ctzll(bits); bits &= bits - 1;
        int j1 = w * 64 + b1x;
        us4 k0 = *(const us4*)&Kb[j0 * 256 + l * 4];
        us4 v0 = *(const us4*)&Vb[j0 * 256 + l * 4];
        us4 k1 = *(const us4*)&Kb[j1 * 256 + l * 4];
        us4 v1 = *(const us4*)&Vb[j1 * 256 + l * 4];
        float s0 = q[0] * bf2f(k0.x) + q[1] * bf2f(k0.y) + q[2] * bf2f(k0.z) + q[3] * bf2f(k0.w);
        float s1 = q[0] * bf2f(k1.x) + q[1] * bf2f(k1.y) + q[2] * bf2f(k1.z) + q[3] * bf2f(k1.w);
#pragma unroll
        for (int off = 1; off <= 32; off <<= 1) {
          s0 += __shfl_xor(s0, off);
          s1 += __shfl_xor(s1, off);
        }
        d += (Kpart[j0] + Kpart[1024 + j0] + Kpart[2048 + j0] + Kpart[3072 + j0]) +
             (Kpart[j1] + Kpart[1024 + j1] + Kpart[2048 + j1] + Kpart[3072 + j1]);
        O[0] += s0 * bf2f(v0.x) + s1 * bf2f(v1.x);
        O[1] += s0 * bf2f(v0.y) + s1 * bf2f(v1.y);
        O[2] += s0 * bf2f(v0.z) + s1 * bf2f(v1.z);
        O[3] += s0 * bf2f(v0.w) + s1 * bf2f(v1.w);
      } else {
        us4 k0 = *(const us4*)&Kb[j0 * 256 + l * 4];
        us4 v0 = *(const us4*)&Vb[j0 * 256 + l * 4];
        float s0 = q[0] * bf2f(k0.x) + q[1] * bf2f(k0.y) + q[2] * bf2f(k0.z) + q[3] * bf2f(k0.w);
#pragma unroll
        for (int off = 1; off <= 32; off <<= 1) s0 += __shfl_xor(s0, off);
        d += Kpart[j0] + Kpart[1024 + j0] + Kpart[2048 + j0] + Kpart[3072 + j0];
        O[0] += s0 * bf2f(v0.x); O[1] += s0 * bf2f(v0.y);
        O[2] += s0 * bf2f(v0.z); O[3] += s0 * bf2f(v0.w);
      }
    }
  }
#pragma unroll
  for (int i = 0; i < 4; i++) S.c.Op[wave][l * 4 + i] = O[i];
  if (l == 0) S.c.dp[wave] = d;
  __syncthreads();
  if (h == 0) {
    float dd = S.c.dp[r] + S.c.dp[r + 4];
    float inv = 1.f / fmaxf(qs * dd, 1e-5f);
    us4 o;
    o.x = f2bf((O[0] + S.c.Op[r + 4][l * 4 + 0]) * inv);
    o.y = f2bf((O[1] + S.c.Op[r + 4][l * 4 + 1]) * inv);
    o.z = f2bf((O[2] + S.c.Op[r + 4][l * 4 + 2]) * inv);
    o.w = f2bf((O[3] + S.c.Op[r + 4][l * 4 + 3]) * inv);
    *(us4*)&S.c.As[r * 264 + l * 4] = o;
  }
  __syncthreads();
  // phase C: 3-layer mish MLP; B-fragments direct from bf16 Wb.
  // A rows 4..15 garbage: D rows >=4 never stored. wave = col-tiles 2w, 2w+1.
#pragma unroll 1
  for (int layer = 0; layer < 3; layer++) {
    const u16* Wl = Wb + layer * 65536;
    const float* bias = (layer == 0) ? b1 : (layer == 1) ? b2 : b3;
    f4 acc2[2];
#pragma unroll
    for (int c = 0; c < 2; c++) {
      const int ntc = wave * 2 + c;
      acc2[c] = (f4){0.f, 0.f, 0.f, 0.f};
#pragma unroll
      for (int kt = 0; kt < 8; kt++) {
        us8 bf = *(const us8*)&Wl[(ntc * 16 + l15) * 256 + kt * 32 + quad * 8];
        acc2[c] = mfma16(&S.c.As[l15 * 264 + kt * 32 + quad * 8], (const u16*)&bf, acc2[c]);
      }
    }
    __syncthreads();
    if (quad == 0) {
#pragma unroll
      for (int c = 0; c < 2; c++) {
        const int n = (wave * 2 + c) * 16 + l15;
        float bv = bias[n];
        if (layer < 2) {
#pragma unroll
          for (int rr = 0; rr < 4; rr++)
            S.c.As[rr * 264 + n] = f2bf(mishf(acc2[c][rr] + bv));
        } else {
#pragma unroll
          for (int rr = 0; rr < 4; rr++)
            S.c.Hbuf[rr * 260 + n] = acc2[c][rr] + bv + SKP[(m0 + rr) * 256 + n];
        }
      }
    }
    __syncthreads();
  }
  // LayerNorm: waves 0..3 = rows
  if (wave < 4) {
    float hv[4];
#pragma unroll
    for (int i = 0; i < 4; i++) hv[i] = S.c.Hbuf[wave * 260 + l * 4 + i];
    float s1 = hv[0] + hv[1] + hv[2] + hv[3];
    float s2 = hv[0] * hv[0] + hv[1] * hv[1] + hv[2] * hv[2] + hv[3] * hv[3];
#pragma unroll
    for (int off = 1; off <= 32; off <<= 1) {
      s1 += __shfl_xor(s1, off);
      s2 += __shfl_xor(s2, off);
    }
    float mu = s1 * (1.f / 256.f);
    float var = s2 * (1.f / 256.f) - mu * mu;
    float rs = rsqrtf(fmaxf(var, 0.f) + 1e-5f);
    float4 wv = *(const float4*)&lnw[l * 4];
    float4 bv = *(const float4*)&lnb[l * 4];
    float4 o;
    o.x = (hv[0] - mu) * rs * wv.x + bv.x;
    o.y = (hv[1] - mu) * rs * wv.y + bv.y;
    o.z = (hv[2] - mu) * rs * wv.z + bv.z;
    o.w = (hv[3] - mu) * rs * wv.w + bv.w;
    *(float4*)&outp[(m0 + wave) * 256 + l * 4] = o;
  }
}

extern "C" void kernel_launch(void* const* d_in, const int* in_sizes, int n_in,
                              void* d_out, int out_size, void* d_ws, size_t ws_size,
                              hipStream_t stream) {
  (void)in_sizes; (void)n_in; (void)out_size; (void)ws_size;
  const float* x   = (const float*)d_in[0];
  const int* start = (const int*)d_in[3];
  const int* done  = (const int*)d_in[4];
  const float* Wk  = (const float*)d_in[5];
  const float* Wq  = (const float*)d_in[6];
  const float* Wv  = (const float*)d_in[7];
  const float* Wsk = (const float*)d_in[8];
  const float* bsk = (const float*)d_in[9];
  const float* W1  = (const float*)d_in[10];
  const float* b1  = (const float*)d_in[11];
  const float* W2  = (const float*)d_in[12];
  const float* b2  = (const float*)d_in[13];
  const float* W3  = (const float*)d_in[14];
  const float* b3  = (const float*)d_in[15];
  const float* lnw = (const float*)d_in[16];
  const float* lnb = (const float*)d_in[17];
  float* out = (float*)d_out;

  char* w = (char*)d_ws;
  u16* Kb      = (u16*)w;                  // 1024x256 bf16
  u16* Qb      = (u16*)(w + 524288);
  u16* Vb      = (u16*)(w + 1048576);
  float* SKP   = (float*)(w + 1572864);    // 1024x256 fp32
  float* Kpart = (float*)(w + 2621440);    // 4x1024 fp32
  u16* Wb      = (u16*)(w + 2637824);      // 3x256x256 bf16 MLP weights
  u32* Flg     = (u32*)(w + 3031040);      // 256 worker-done flags

  fused2<<<512, 512, 0, stream>>>(x, Wk, Wq, Wv, Wsk, bsk, start, done,
                                  W1, W2, W3, b1, b2, b3, lnw, lnb,
                                  Kb, Qb, Vb, SKP, Kpart, Wb, Flg, out);
}

// Round 15
// 129.228 us; speedup vs baseline: 3.2926x; 3.2926x over previous
//
#include <hip/hip_runtime.h>
#include <math.h>

// LinearAttention: T=1024, D=256, H=256.  R15: recombination of proven parts.
// combine() is NOT associative; replicate JAX's odd-even bracketing.
// s0=z0=0 -> s_t = sum_j W[t][j] k_j v_j^T; denom_t = (sum_j W[t][j] Ksum_j)*Qsum_t.
// Structure verdict after R11 (coop: +70us), R13 (redundant: +60us), R14
// (spin flags: +300us): two plain dispatches is the skeleton. R15 pairs
// R12's K1 (512-thr 8-wave dbuf staging, 1 barrier/kt; proven correct in R12)
// with R10's K2 (256 blocks, preamble-free; best measured K2) — never yet
// paired together.

typedef unsigned long long u64;
typedef unsigned short u16;
typedef __attribute__((ext_vector_type(8))) unsigned short us8;
typedef __attribute__((ext_vector_type(4))) unsigned short us4;
typedef __attribute__((ext_vector_type(8))) short s8;
typedef __attribute__((ext_vector_type(4))) float f4;

__device__ __forceinline__ float eluf(float v) { return v > 0.f ? v : expm1f(v); }
__device__ __forceinline__ float mishf(float v) {
  float sp = fmaxf(v, 0.f) + log1pf(expf(-fabsf(v)));
  return v * tanhf(sp);
}
__device__ __forceinline__ u16 f2bf(float f) {
  unsigned u = __float_as_uint(f);
  unsigned r = u + 0x7FFFu + ((u >> 16) & 1u);
  return (u16)(r >> 16);
}
__device__ __forceinline__ float bf2f(u16 h) { return __uint_as_float((unsigned)h << 16); }

__device__ __forceinline__ f4 mfma16(const u16* a, const u16* b, f4 c) {
  s8 av = *(const s8*)(const void*)a;
  s8 bv = *(const s8*)(const void*)b;
  return __builtin_amdgcn_mfma_f32_16x16x32_bf16(av, bv, c, 0, 0, 0);
}

__device__ __forceinline__ u64 expand32(u64 x) {
  x &= 0xFFFFFFFFull;
  x = (x | (x << 16)) & 0x0000FFFF0000FFFFull;
  x = (x | (x << 8))  & 0x00FF00FF00FF00FFull;
  x = (x | (x << 4))  & 0x0F0F0F0F0F0F0F0Full;
  x = (x | (x << 2))  & 0x3333333333333333ull;
  x = (x | (x << 1))  & 0x5555555555555555ull;
  return x | (x << 1);
}

__device__ __forceinline__ us8 cvt8v(float4 a, float4 b) {
  us8 v;
  v[0] = f2bf(a.x); v[1] = f2bf(a.y); v[2] = f2bf(a.z); v[3] = f2bf(a.w);
  v[4] = f2bf(b.x); v[5] = f2bf(b.y); v[6] = f2bf(b.z); v[7] = f2bf(b.w);
  return v;
}

// ---- K1 (R12-proven): K=elu(xWk^T) Q=elu(xWq^T) V=xWv^T SKP=xWskip^T+b,
// Kpart rowsums, + side-job W1/W2/W3 -> bf16 Wb. grid(256) x 512 thr (8 waves).
// Staging: 512 us8 slots, double-buffered -> ONE barrier per kt.
__global__ __launch_bounds__(512) void qkvs_mfma(const float* __restrict__ x,
    const float* __restrict__ Wk, const float* __restrict__ Wq,
    const float* __restrict__ Wv, const float* __restrict__ Wsk,
    const float* __restrict__ bskip,
    const float* __restrict__ W1, const float* __restrict__ W2, const float* __restrict__ W3,
    u16* __restrict__ Kb, u16* __restrict__ Qb, u16* __restrict__ Vb,
    float* __restrict__ SKP, float* __restrict__ Kpart, u16* __restrict__ Wb) {
  __shared__ u16 Xs[2][64 * 40], Ws[2][64 * 40];
  __shared__ float scrK[128];
  const int tid = threadIdx.x, wave = tid >> 6, l = tid & 63;
  const int l15 = l & 15, quad = l >> 4;
  const int rt = blockIdx.x & 15, my = blockIdx.x >> 4;
  const int mat = my >> 2, nt = my & 3;
  const int n0 = nt * 64, mbase = rt * 64;
  const float* Wsrc = (mat == 0) ? Wk : (mat == 1) ? Wq : (mat == 2) ? Wv : Wsk;
  if (tid < 192) {  // side-job: bf16-convert MLP weights
    int cidx = blockIdx.x * 768 + tid * 4;
    const float* Wm = (cidx < 65536) ? W1 : (cidx < 131072) ? W2 : W3;
    float4 v = *(const float4*)(Wm + (cidx & 65535));
    us4 o; o.x = f2bf(v.x); o.y = f2bf(v.y); o.z = f2bf(v.z); o.w = f2bf(v.w);
    *(us4*)&Wb[cidx] = o;
  }
  // staging slot: threads 0..255 -> A (x), 256..511 -> B (Wsrc)
  const int sidx = tid & 255, srow = sidx >> 2, sko = (sidx & 3) * 8;
  const int isB = tid >> 8;
  const float* src = (isB ? Wsrc + (size_t)(n0 + srow) * 256
                          : x + (size_t)(mbase + srow) * 256) + sko;
  u16* dstb = (isB ? &Ws[0][0] : &Xs[0][0]) + srow * 40 + sko;
  const int st = wave & 3, sh = (wave >> 2) * 2;
  f4 acc0 = (f4){0.f, 0.f, 0.f, 0.f}, acc1 = (f4){0.f, 0.f, 0.f, 0.f};
  float4 pa = *(const float4*)src, pb = *(const float4*)(src + 4);
#pragma unroll 1
  for (int kt = 0; kt < 8; kt++) {
    const int p = kt & 1;
    *(us8*)(dstb + p * 2560) = cvt8v(pa, pb);
    if (kt < 7) {
      pa = *(const float4*)(src + (kt + 1) * 32);
      pb = *(const float4*)(src + (kt + 1) * 32 + 4);
    }
    __syncthreads();
    const u16* ap = &Xs[p][(st * 16 + l15) * 40 + quad * 8];
    acc0 = mfma16(ap, &Ws[p][(sh * 16 + l15) * 40 + quad * 8], acc0);
    acc1 = mfma16(ap, &Ws[p][((sh + 1) * 16 + l15) * 40 + quad * 8], acc1);
  }
  // epilogue: rows mw..mw+3, col tiles sh, sh+1
  const int mw = mbase + st * 16 + quad * 4;
  if (mat == 0) {
    float tw[4];
#pragma unroll
    for (int r = 0; r < 4; r++) {
      float v0 = eluf(acc0[r]), v1 = eluf(acc1[r]);
      Kb[(mw + r) * 256 + n0 + sh * 16 + l15] = f2bf(v0);
      Kb[(mw + r) * 256 + n0 + (sh + 1) * 16 + l15] = f2bf(v1);
      tw[r] = v0 + v1;
    }
#pragma unroll
    for (int r = 0; r < 4; r++) {
      float t = tw[r];
#pragma unroll
      for (int off = 1; off <= 8; off <<= 1) t += __shfl_xor(t, off);
      if (l15 == 0) scrK[st * 32 + (wave >> 2) * 16 + quad * 4 + r] = t;
    }
    __syncthreads();
    if (wave < 4 && l < 16)
      Kpart[nt * 1024 + mbase + wave * 16 + l] = scrK[wave * 32 + l] + scrK[wave * 32 + 16 + l];
  } else if (mat == 1) {
#pragma unroll
    for (int r = 0; r < 4; r++) {
      Qb[(mw + r) * 256 + n0 + sh * 16 + l15] = f2bf(eluf(acc0[r]));
      Qb[(mw + r) * 256 + n0 + (sh + 1) * 16 + l15] = f2bf(eluf(acc1[r]));
    }
  } else if (mat == 2) {
#pragma unroll
    for (int r = 0; r < 4; r++) {
      Vb[(mw + r) * 256 + n0 + sh * 16 + l15] = f2bf(acc0[r]);
      Vb[(mw + r) * 256 + n0 + (sh + 1) * 16 + l15] = f2bf(acc1[r]);
    }
  } else {
    float bv0 = bskip[n0 + sh * 16 + l15], bv1 = bskip[n0 + (sh + 1) * 16 + l15];
#pragma unroll
    for (int r = 0; r < 4; r++) {
      SKP[(mw + r) * 256 + n0 + sh * 16 + l15] = acc0[r] + bv0;
      SKP[(mw + r) * 256 + n0 + (sh + 1) * 16 + l15] = acc1[r] + bv1;
    }
  }
}

// ---- K2 (R10-proven): self-derived mask + sparse attention + fused MLP + LN.
// grid(256) x 512 (8 waves). 4 rows/block; waves r, r+4 split row r's words.
__global__ __launch_bounds__(512) void attn_mlp(
    const u16* __restrict__ Kb, const u16* __restrict__ Qb, const u16* __restrict__ Vb,
    const float* __restrict__ Kpart, const float* __restrict__ SKP,
    const int* __restrict__ start, const int* __restrict__ done,
    const u16* __restrict__ Wb,
    const float* __restrict__ b1, const float* __restrict__ b2, const float* __restrict__ b3,
    const float* __restrict__ lnw, const float* __restrict__ lnb,
    float* __restrict__ outp) {
  __shared__ u64 GS[37];
  __shared__ u64 Mw[64];
  __shared__ u16 As[16 * 264];
  __shared__ float Op[8][256];
  __shared__ float dp[8];
  __shared__ float Hbuf[4 * 260];
  const int tid = threadIdx.x, wave = tid >> 6, l = tid & 63;
  const int l15 = l & 15, quad = l >> 4;
  const int m0 = blockIdx.x * 4;
  // gates via ballot, direct global reads
  for (int job = wave; job < 37; job += 8) {
    int lv, w;
    if (job < 17)      { lv = 0; w = job; }
    else if (job < 25) { lv = 1; w = job - 17; }
    else if (job < 29) { lv = 2; w = job - 25; }
    else if (job < 31) { lv = 3; w = job - 29; }
    else               { lv = job - 27; w = 0; }
    int n = 1024 >> lv;
    int j = w * 64 + l;
    int ok = 0;
    if (j < n)
      ok = (j & 1) ? (done[((j + 1) << lv) - 1] != 0) : (start[((j + 2) << lv) - 1] != 0);
    u64 word = __ballot(ok != 0);
    if (l == 0) GS[(lv == 0) ? w : (lv == 1) ? 17 + w : (lv == 2) ? 25 + w
                   : (lv == 3) ? 29 + w : 27 + lv] = word;
  }
  __syncthreads();
  // wave-local ancestor chains. waves 0..3 = rows m0+wave+1.
  const int GOFF2[10] = {0, 17, 25, 29, 31, 32, 33, 34, 35, 36};
  if (wave < 4) {
    const int t = m0 + wave + 1;
    int rr10 = t;
#pragma unroll
    for (int qq = 0; qq < 10; qq++) rr10 = (rr10 & 1) ? (rr10 >> 1) : (rr10 >> 1) - 1;
    u64 cur = (l == 0 && rr10 == 0) ? 1ull : 0ull;
#pragma unroll 1
    for (int lv = 9; lv >= 1; lv--) {
      int rr = t;
      for (int qq = 0; qq < lv; qq++) rr = (rr & 1) ? (rr >> 1) : (rr >> 1) - 1;
      const int nw = (lv >= 4) ? 1 : (8 >> (lv - 1));
      u64 pw = __shfl(cur, l >> 1);
      u64 word;
      if (rr <= 0) word = (l == 0 && rr == 0) ? 1ull : 0ull;
      else {
        u64 e = 0;
        if (l < nw) e = expand32((l & 1) ? (pw >> 32) : pw) & GS[GOFF2[lv] + l];
        if (rr & 1) word = e;
        else {
          int gi = ((rr + 1) << lv) - 1;
          word = (start[gi] != 0) ? e : 0ull;
          if ((rr >> 6) == l) word |= (u64)(done[gi] != 0) << (rr & 63);
        }
        if (l >= nw) word = 0ull;
      }
      cur = word;
    }
    u64 pw = __shfl(cur, (l >> 1) & 7);
    u64 uw = 0;
    if (l <= 16) {
      u64 e = 0;
      if (l < 16) e = expand32((l & 1) ? (pw >> 32) : pw) & GS[l];
      if (t & 1) uw = e;
      else {
        uw = (start[t] != 0) ? e : 0ull;
        if ((t >> 6) == l) uw |= (u64)(done[t] != 0) << (t & 63);
      }
    }
    u64 nxt = __shfl(uw, (l + 1) & 63);
    u64 mw0 = (uw >> 1) | (nxt << 63);
    if (l < 16) Mw[wave * 16 + l] = mw0;
  }
  __syncthreads();
  // phase B: sparse gather, 2-bit ILP; d from Kpart at set bits only.
  const int r = wave & 3, h = wave >> 2;
  const int tp = m0 + r;
  float q[4], O[4] = {0.f, 0.f, 0.f, 0.f};
  {
    us4 qv = *(const us4*)&Qb[tp * 256 + l * 4];
    q[0] = bf2f(qv.x); q[1] = bf2f(qv.y); q[2] = bf2f(qv.z); q[3] = bf2f(qv.w);
  }
  float qs = q[0] + q[1] + q[2] + q[3];
#pragma unroll
  for (int off = 1; off <= 32; off <<= 1) qs += __shfl_xor(qs, off);
  float d = 0.f;
  for (int w = h * 8; w < h * 8 + 8; w++) {
    u64 bits = Mw[r * 16 + w];
    while (bits) {
      int b0 = __builtin_ctzll(bits); bits &= bits - 1;
      int j0 = w * 64 + b0;
      if (bits) {
        int b1x = __builtin_ctzll(bits); bits &= bits - 1;
        int j1 = w * 64 + b1x;
        us4 k0 = *(const us4*)&Kb[j0 * 256 + l * 4];
        us4 v0 = *(const us4*)&Vb[j0 * 256 + l * 4];
        us4 k1 = *(const us4*)&Kb[j1 * 256 + l * 4];
        us4 v1 = *(const us4*)&Vb[j1 * 256 + l * 4];
        float s0 = q[0] * bf2f(k0.x) + q[1] * bf2f(k0.y) + q[2] * bf2f(k0.z) + q[3] * bf2f(k0.w);
        float s1 = q[0] * bf2f(k1.x) + q[1] * bf2f(k1.y) + q[2] * bf2f(k1.z) + q[3] * bf2f(k1.w);
#pragma unroll
        for (int off = 1; off <= 32; off <<= 1) {
          s0 += __shfl_xor(s0, off);
          s1 += __shfl_xor(s1, off);
        }
        d += (Kpart[j0] + Kpart[1024 + j0] + Kpart[2048 + j0] + Kpart[3072 + j0]) +
             (Kpart[j1] + Kpart[1024 + j1] + Kpart[2048 + j1] + Kpart[3072 + j1]);
        O[0] += s0 * bf2f(v0.x) + s1 * bf2f(v1.x);
        O[1] += s0 * bf2f(v0.y) + s1 * bf2f(v1.y);
        O[2] += s0 * bf2f(v0.z) + s1 * bf2f(v1.z);
        O[3] += s0 * bf2f(v0.w) + s1 * bf2f(v1.w);
      } else {
        us4 k0 = *(const us4*)&Kb[j0 * 256 + l * 4];
        us4 v0 = *(const us4*)&Vb[j0 * 256 + l * 4];
        float s0 = q[0] * bf2f(k0.x) + q[1] * bf2f(k0.y) + q[2] * bf2f(k0.z) + q[3] * bf2f(k0.w);
#pragma unroll
        for (int off = 1; off <= 32; off <<= 1) s0 += __shfl_xor(s0, off);
        d += Kpart[j0] + Kpart[1024 + j0] + Kpart[2048 + j0] + Kpart[3072 + j0];
        O[0] += s0 * bf2f(v0.x); O[1] += s0 * bf2f(v0.y);
        O[2] += s0 * bf2f(v0.z); O[3] += s0 * bf2f(v0.w);
      }
    }
  }
#pragma unroll
  for (int i = 0; i < 4; i++) Op[wave][l * 4 + i] = O[i];
  if (l == 0) dp[wave] = d;
  __syncthreads();
  if (h == 0) {
    float dd = dp[r] + dp[r + 4];
    float inv = 1.f / fmaxf(qs * dd, 1e-5f);
    us4 o;
    o.x = f2bf((O[0] + Op[r + 4][l * 4 + 0]) * inv);
    o.y = f2bf((O[1] + Op[r + 4][l * 4 + 1]) * inv);
    o.z = f2bf((O[2] + Op[r + 4][l * 4 + 2]) * inv);
    o.w = f2bf((O[3] + Op[r + 4][l * 4 + 3]) * inv);
    *(us4*)&As[r * 264 + l * 4] = o;
  }
  __syncthreads();
  // phase C: 3-layer mish MLP; B-fragments direct from bf16 Wb.
  // A rows 4..15 garbage: D rows >=4 never stored. wave = col-tiles 2w, 2w+1.
#pragma unroll 1
  for (int layer = 0; layer < 3; layer++) {
    const u16* Wl = Wb + layer * 65536;
    const float* bias = (layer == 0) ? b1 : (layer == 1) ? b2 : b3;
    f4 acc2[2];
#pragma unroll
    for (int c = 0; c < 2; c++) {
      const int ntc = wave * 2 + c;
      acc2[c] = (f4){0.f, 0.f, 0.f, 0.f};
#pragma unroll
      for (int kt = 0; kt < 8; kt++) {
        us8 bf = *(const us8*)&Wl[(ntc * 16 + l15) * 256 + kt * 32 + quad * 8];
        acc2[c] = mfma16(&As[l15 * 264 + kt * 32 + quad * 8], (const u16*)&bf, acc2[c]);
      }
    }
    __syncthreads();
    if (quad == 0) {
#pragma unroll
      for (int c = 0; c < 2; c++) {
        const int n = (wave * 2 + c) * 16 + l15;
        float bv = bias[n];
        if (layer < 2) {
#pragma unroll
          for (int rr = 0; rr < 4; rr++)
            As[rr * 264 + n] = f2bf(mishf(acc2[c][rr] + bv));
        } else {
#pragma unroll
          for (int rr = 0; rr < 4; rr++)
            Hbuf[rr * 260 + n] = acc2[c][rr] + bv + SKP[(m0 + rr) * 256 + n];
        }
      }
    }
    __syncthreads();
  }
  // LayerNorm: waves 0..3 = rows
  if (wave < 4) {
    float hv[4];
#pragma unroll
    for (int i = 0; i < 4; i++) hv[i] = Hbuf[wave * 260 + l * 4 + i];
    float s1 = hv[0] + hv[1] + hv[2] + hv[3];
    float s2 = hv[0] * hv[0] + hv[1] * hv[1] + hv[2] * hv[2] + hv[3] * hv[3];
#pragma unroll
    for (int off = 1; off <= 32; off <<= 1) {
      s1 += __shfl_xor(s1, off);
      s2 += __shfl_xor(s2, off);
    }
    float mu = s1 * (1.f / 256.f);
    float var = s2 * (1.f / 256.f) - mu * mu;
    float rs = rsqrtf(fmaxf(var, 0.f) + 1e-5f);
    float4 wv = *(const float4*)&lnw[l * 4];
    float4 bv = *(const float4*)&lnb[l * 4];
    float4 o;
    o.x = (hv[0] - mu) * rs * wv.x + bv.x;
    o.y = (hv[1] - mu) * rs * wv.y + bv.y;
    o.z = (hv[2] - mu) * rs * wv.z + bv.z;
    o.w = (hv[3] - mu) * rs * wv.w + bv.w;
    *(float4*)&outp[(m0 + wave) * 256 + l * 4] = o;
  }
}

extern "C" void kernel_launch(void* const* d_in, const int* in_sizes, int n_in,
                              void* d_out, int out_size, void* d_ws, size_t ws_size,
                              hipStream_t stream) {
  (void)in_sizes; (void)n_in; (void)out_size; (void)ws_size;
  const float* x   = (const float*)d_in[0];
  const int* start = (const int*)d_in[3];
  const int* done  = (const int*)d_in[4];
  const float* Wk  = (const float*)d_in[5];
  const float* Wq  = (const float*)d_in[6];
  const float* Wv  = (const float*)d_in[7];
  const float* Wsk = (const float*)d_in[8];
  const float* bsk = (const float*)d_in[9];
  const float* W1  = (const float*)d_in[10];
  const float* b1  = (const float*)d_in[11];
  const float* W2  = (const float*)d_in[12];
  const float* b2  = (const float*)d_in[13];
  const float* W3  = (const float*)d_in[14];
  const float* b3  = (const float*)d_in[15];
  const float* lnw = (const float*)d_in[16];
  const float* lnb = (const float*)d_in[17];
  float* out = (float*)d_out;

  char* w = (char*)d_ws;
  u16* Kb      = (u16*)w;                  // 1024x256 bf16
  u16* Qb      = (u16*)(w + 524288);
  u16* Vb      = (u16*)(w + 1048576);
  float* SKP   = (float*)(w + 1572864);    // 1024x256 fp32
  float* Kpart = (float*)(w + 2621440);    // 4x1024 fp32
  u16* Wb      = (u16*)(w + 2637824);      // 3x256x256 bf16 MLP weights

  qkvs_mfma<<<256, 512, 0, stream>>>(x, Wk, Wq, Wv, Wsk, bsk, W1, W2, W3,
                                     Kb, Qb, Vb, SKP, Kpart, Wb);
  attn_mlp<<<256, 512, 0, stream>>>(Kb, Qb, Vb, Kpart, SKP, start, done, Wb,
                                    b1, b2, b3, lnw, lnb, out);
}